// Round 6
// baseline (1676.896 us; speedup 1.0000x reference)
//
#include <hip/hip_runtime.h>

#define NN 200000
#define NE 6400000
#define FIN 256
#define HID 16
#define NC 40
#define NBKT 782        // ceil(NN/256) dst-buckets of 256 nodes
#define NCHUNK 2048     // histogram microchunks
#define EPC 3125        // edges per microchunk: 2048*3125 = 6.4M exact
#define CPT 8           // chunks per thread in btotal/cscan (2048/256)
#define SC_BLOCKS 512   // scatter blocks (2 per CU)
#define SC_THREADS 512
#define MC_PER_BLK 4    // microchunks per scatter block (12500 edges, runs ~16/bucket)

// ---- 1. per-microchunk coarse histogram over 782 dst-buckets (LDS atomics only) ----
__global__ __launch_bounds__(256) void k_chist(const int* __restrict__ dst,
                                               int* __restrict__ hist_g) {
    __shared__ int sh[NBKT];
    int c = blockIdx.x;
    for (int j = threadIdx.x; j < NBKT; j += 256) sh[j] = 0;
    __syncthreads();
    int beg = c * EPC;
    int end = min(beg + EPC, NE);
    for (int e = beg + threadIdx.x; e < end; e += 256)
        atomicAdd(&sh[dst[e] >> 8], 1);
    __syncthreads();
    for (int j = threadIdx.x; j < NBKT; j += 256)
        hist_g[c * NBKT + j] = sh[j];
}

// ---- 2. bucket totals: block per bucket, tree reduce over 2048 chunks ----
__global__ __launch_bounds__(256) void k_btotal(const int* __restrict__ hist_g,
                                                int* __restrict__ totals) {
    __shared__ int sm[256];
    int b = blockIdx.x, t = threadIdx.x;
    int s = 0;
#pragma unroll
    for (int j = 0; j < CPT; ++j)
        s += hist_g[(t * CPT + j) * NBKT + b];
    sm[t] = s;
    __syncthreads();
    for (int off = 128; off > 0; off >>= 1) {
        if (t < off) sm[t] += sm[t + off];
        __syncthreads();
    }
    if (t == 0) totals[b] = sm[0];
}

// ---- 3. exclusive scan of 782 totals -> binBase ----
__global__ __launch_bounds__(1024) void k_bscan(const int* __restrict__ totals,
                                                int* __restrict__ binBase) {
    __shared__ int sm[1024];
    int t = threadIdx.x;
    int v = (t < NBKT) ? totals[t] : 0;
    sm[t] = v;
    __syncthreads();
    for (int off = 1; off < 1024; off <<= 1) {
        int x = (t >= off) ? sm[t - off] : 0;
        __syncthreads();
        sm[t] += x;
        __syncthreads();
    }
    if (t < NBKT) binBase[t] = sm[t] - v;
    if (t == 0) binBase[NBKT] = NE;
}

// ---- 4. per-bucket scan over 2048 microchunks, in place: hist -> cursor bases ----
__global__ __launch_bounds__(256) void k_cscan(int* __restrict__ hist_g,
                                               const int* __restrict__ binBase) {
    __shared__ int sm[256];
    int b = blockIdx.x, t = threadIdx.x;
    int loc[CPT];
    int s = 0;
#pragma unroll
    for (int j = 0; j < CPT; ++j) {
        loc[j] = hist_g[(t * CPT + j) * NBKT + b];
        s += loc[j];
    }
    sm[t] = s;
    __syncthreads();
    for (int off = 1; off < 256; off <<= 1) {
        int x = (t >= off) ? sm[t - off] : 0;
        __syncthreads();
        sm[t] += x;
        __syncthreads();
    }
    int base = binBase[b] + sm[t] - s;
#pragma unroll
    for (int j = 0; j < CPT; ++j) {
        hist_g[(t * CPT + j) * NBKT + b] = base;
        base += loc[j];
    }
}

// ---- 5. coarse scatter: group edges by dst-bucket; record = {src | dl<<18, w}.
// 4 consecutive microchunks per block; cursor seed = first microchunk's base
// (pooled range == union of the 4 ranges since the scan is chunk-order cumulative).
__global__ __launch_bounds__(512) void k_cscatter(const int* __restrict__ src,
                                                  const int* __restrict__ dst,
                                                  const float* __restrict__ w,
                                                  const int* __restrict__ coff,
                                                  int2* __restrict__ ebuf) {
    __shared__ int scur[NBKT];
    int c = blockIdx.x;
    int mc0 = c * MC_PER_BLK;
    for (int j = threadIdx.x; j < NBKT; j += SC_THREADS)
        scur[j] = coff[mc0 * NBKT + j];
    __syncthreads();
    int beg = mc0 * EPC;
    int end = min(beg + MC_PER_BLK * EPC, NE);
    for (int e = beg + threadIdx.x; e < end; e += SC_THREADS) {
        int d = dst[e];
        int pos = atomicAdd(&scur[d >> 8], 1);
        ebuf[pos] = make_int2(src[e] | ((d & 255) << 18), __float_as_int(w[e]));
    }
}

// ---- 6. per-bucket weighted degree -> dinv (LDS f32 atomics, 256 bins) ----
__global__ __launch_bounds__(256) void k_deg(const int* __restrict__ binBase,
                                             const int2* __restrict__ ebuf,
                                             float* __restrict__ dinv) {
    __shared__ float sdeg[256];
    int b = blockIdx.x, t = threadIdx.x;
    sdeg[t] = 1.0f;  // self-loop weight
    __syncthreads();
    int beg = binBase[b], end = binBase[b + 1];
    for (int e = beg + t; e < end; e += 256) {
        int2 r = ebuf[e];
        atomicAdd(&sdeg[(r.x >> 18) & 255], __int_as_float(r.y));
    }
    __syncthreads();
    int node = b * 256 + t;
    if (node < NN) dinv[node] = rsqrtf(sdeg[t]);  // deg >= 1 always
}

// ---- 7. h' = dinv[row] * (x @ W1) ----
__global__ __launch_bounds__(256) void k_gemm1(const float* __restrict__ x,
                                               const float* __restrict__ W1,
                                               const float* __restrict__ dinv,
                                               float* __restrict__ hp) {
    int row = blockIdx.x * 256 + threadIdx.x;
    if (row >= NN) return;
    float acc[HID];
#pragma unroll
    for (int f = 0; f < HID; ++f) acc[f] = 0.0f;
    const float4* x4 = reinterpret_cast<const float4*>(x + (size_t)row * FIN);
    for (int kk = 0; kk < FIN / 4; ++kk) {
        float4 xv = x4[kk];
#pragma unroll
        for (int j = 0; j < 4; ++j) {
            float xs = (j == 0) ? xv.x : (j == 1) ? xv.y : (j == 2) ? xv.z : xv.w;
            int k = kk * 4 + j;
#pragma unroll
            for (int f = 0; f < HID; ++f)
                acc[f] = fmaf(xs, W1[k * HID + f], acc[f]);
        }
    }
    float di = dinv[row];
    float4* out4 = reinterpret_cast<float4*>(hp + (size_t)row * HID);
#pragma unroll
    for (int q = 0; q < HID / 4; ++q)
        out4[q] = make_float4(acc[q*4]*di, acc[q*4+1]*di, acc[q*4+2]*di, acc[q*4+3]*di);
}

// ---- 8. layer-1 aggregation, block per bucket, LDS f-major accumulator.
// h1'[d] = dinv[d] * relu( dinv[d]*(acc[d] + h'[d]) + b1 )
__global__ __launch_bounds__(256) void k_agg1(const int* __restrict__ binBase,
                                              const int2* __restrict__ ebuf,
                                              const float* __restrict__ hp,
                                              const float* __restrict__ dinv,
                                              const float* __restrict__ b1,
                                              float* __restrict__ h1p) {
    __shared__ float acc[HID][256];   // f-major: bank = dl%32, random dl -> ~2-way
    int b = blockIdx.x, t = threadIdx.x;
#pragma unroll
    for (int f = 0; f < HID; ++f) acc[f][t] = 0.0f;
    __syncthreads();
    int beg = binBase[b], end = binBase[b + 1];
    for (int e = beg + t; e < end; e += 256) {
        int2 r = ebuf[e];
        int s = r.x & 0x3FFFF;
        int dl = (r.x >> 18) & 255;
        float wv = __int_as_float(r.y);
        const float4* hv = reinterpret_cast<const float4*>(hp + (size_t)s * HID);
        float4 v0 = hv[0], v1 = hv[1], v2 = hv[2], v3 = hv[3];
        atomicAdd(&acc[ 0][dl], v0.x * wv); atomicAdd(&acc[ 1][dl], v0.y * wv);
        atomicAdd(&acc[ 2][dl], v0.z * wv); atomicAdd(&acc[ 3][dl], v0.w * wv);
        atomicAdd(&acc[ 4][dl], v1.x * wv); atomicAdd(&acc[ 5][dl], v1.y * wv);
        atomicAdd(&acc[ 6][dl], v1.z * wv); atomicAdd(&acc[ 7][dl], v1.w * wv);
        atomicAdd(&acc[ 8][dl], v2.x * wv); atomicAdd(&acc[ 9][dl], v2.y * wv);
        atomicAdd(&acc[10][dl], v2.z * wv); atomicAdd(&acc[11][dl], v2.w * wv);
        atomicAdd(&acc[12][dl], v3.x * wv); atomicAdd(&acc[13][dl], v3.y * wv);
        atomicAdd(&acc[14][dl], v3.z * wv); atomicAdd(&acc[15][dl], v3.w * wv);
    }
    __syncthreads();
    int i = b * 256 + t;
    if (i < NN) {
        float di = dinv[i];
        const float4* hv = reinterpret_cast<const float4*>(hp + (size_t)i * HID);
        float4* o4 = reinterpret_cast<float4*>(h1p + (size_t)i * HID);
#pragma unroll
        for (int q = 0; q < 4; ++q) {
            float4 hs = hv[q];
            float4 r;
            r.x = di * fmaxf(di * (acc[q*4+0][t] + hs.x) + b1[q*4+0], 0.0f);
            r.y = di * fmaxf(di * (acc[q*4+1][t] + hs.y) + b1[q*4+1], 0.0f);
            r.z = di * fmaxf(di * (acc[q*4+2][t] + hs.z) + b1[q*4+2], 0.0f);
            r.w = di * fmaxf(di * (acc[q*4+3][t] + hs.w) + b1[q*4+3], 0.0f);
            o4[q] = r;
        }
    }
}

// ---- 9. layer-2 aggregation fused with GEMM2:
// out[d] = ( dinv[d]*(acc[d] + h1'[d]) ) @ W2 + b2
__global__ __launch_bounds__(256) void k_agg2(const int* __restrict__ binBase,
                                              const int2* __restrict__ ebuf,
                                              const float* __restrict__ h1p,
                                              const float* __restrict__ dinv,
                                              const float* __restrict__ W2,
                                              const float* __restrict__ b2,
                                              float* __restrict__ out) {
    __shared__ float acc[HID][256];
    __shared__ float sW2[HID * NC];
    __shared__ float sb2[NC];
    int b = blockIdx.x, t = threadIdx.x;
#pragma unroll
    for (int f = 0; f < HID; ++f) acc[f][t] = 0.0f;
    for (int j = t; j < HID * NC; j += 256) sW2[j] = W2[j];
    if (t < NC) sb2[t] = b2[t];
    __syncthreads();
    int beg = binBase[b], end = binBase[b + 1];
    for (int e = beg + t; e < end; e += 256) {
        int2 r = ebuf[e];
        int s = r.x & 0x3FFFF;
        int dl = (r.x >> 18) & 255;
        float wv = __int_as_float(r.y);
        const float4* hv = reinterpret_cast<const float4*>(h1p + (size_t)s * HID);
        float4 v0 = hv[0], v1 = hv[1], v2 = hv[2], v3 = hv[3];
        atomicAdd(&acc[ 0][dl], v0.x * wv); atomicAdd(&acc[ 1][dl], v0.y * wv);
        atomicAdd(&acc[ 2][dl], v0.z * wv); atomicAdd(&acc[ 3][dl], v0.w * wv);
        atomicAdd(&acc[ 4][dl], v1.x * wv); atomicAdd(&acc[ 5][dl], v1.y * wv);
        atomicAdd(&acc[ 6][dl], v1.z * wv); atomicAdd(&acc[ 7][dl], v1.w * wv);
        atomicAdd(&acc[ 8][dl], v2.x * wv); atomicAdd(&acc[ 9][dl], v2.y * wv);
        atomicAdd(&acc[10][dl], v2.z * wv); atomicAdd(&acc[11][dl], v2.w * wv);
        atomicAdd(&acc[12][dl], v3.x * wv); atomicAdd(&acc[13][dl], v3.y * wv);
        atomicAdd(&acc[14][dl], v3.z * wv); atomicAdd(&acc[15][dl], v3.w * wv);
    }
    __syncthreads();
    int i = b * 256 + t;
    if (i < NN) {
        float di = dinv[i];
        const float4* hv = reinterpret_cast<const float4*>(h1p + (size_t)i * HID);
        float v[HID];
#pragma unroll
        for (int q = 0; q < 4; ++q) {
            float4 hs = hv[q];
            v[q*4+0] = di * (acc[q*4+0][t] + hs.x);
            v[q*4+1] = di * (acc[q*4+1][t] + hs.y);
            v[q*4+2] = di * (acc[q*4+2][t] + hs.z);
            v[q*4+3] = di * (acc[q*4+3][t] + hs.w);
        }
        float o[NC];
#pragma unroll
        for (int c = 0; c < NC; ++c) o[c] = sb2[c];
#pragma unroll
        for (int k = 0; k < HID; ++k) {
#pragma unroll
            for (int c = 0; c < NC; ++c)
                o[c] = fmaf(v[k], sW2[k * NC + c], o[c]);
        }
        float4* op = reinterpret_cast<float4*>(out + (size_t)i * NC);
#pragma unroll
        for (int q = 0; q < NC / 4; ++q)
            op[q] = make_float4(o[q*4], o[q*4+1], o[q*4+2], o[q*4+3]);
    }
}

// ---- launch ----
extern "C" void kernel_launch(void* const* d_in, const int* in_sizes, int n_in,
                              void* d_out, int out_size, void* d_ws, size_t ws_size,
                              hipStream_t stream) {
    const float* x  = (const float*)d_in[0];
    const int*   ei = (const int*)d_in[1];
    const float* w  = (const float*)d_in[2];
    const float* W1 = (const float*)d_in[3];
    const float* b1 = (const float*)d_in[4];
    const float* W2 = (const float*)d_in[5];
    const float* b2 = (const float*)d_in[6];
    float* out = (float*)d_out;

    const int* src = ei;
    const int* dst = ei + NE;

    // workspace layout (4B words), total 19.4M words = 77.6 MB.
    // hist_g (2048*782 = 1,601,536 words) ALIASED into hp region
    // (hist_g dead after k_cscatter; hp first written by k_gemm1, later).
    char* wsb = (char*)d_ws;
    float* dinv    = (float*)(wsb);                      // 200064
    int*   totals  = (int*)  (wsb + 200064LL * 4);       // 1024
    int*   binBase = (int*)  (wsb + 201088LL * 4);       // 1024 (NBKT+1 used)
    int2*  ebuf    = (int2*) (wsb + 202112LL * 4);       // NE int2 = 12.8M words
    float* hp      = (float*)(wsb + 13002112LL * 4);     // NN*HID (3.2M words)
    int*   hist_g  = (int*)  (wsb + 13002112LL * 4);     // aliases hp (1.6M <= 3.2M)
    float* h1p     = (float*)(wsb + 16202112LL * 4);     // NN*HID

    const int BN = (NN + 255) / 256;   // 782

    k_chist   <<<NCHUNK, 256, 0, stream>>>(dst, hist_g);
    k_btotal  <<<NBKT, 256, 0, stream>>>(hist_g, totals);
    k_bscan   <<<1, 1024, 0, stream>>>(totals, binBase);
    k_cscan   <<<NBKT, 256, 0, stream>>>(hist_g, binBase);
    k_cscatter<<<SC_BLOCKS, SC_THREADS, 0, stream>>>(src, dst, w, hist_g, ebuf);
    k_deg     <<<NBKT, 256, 0, stream>>>(binBase, ebuf, dinv);
    k_gemm1   <<<BN, 256, 0, stream>>>(x, W1, dinv, hp);
    k_agg1    <<<NBKT, 256, 0, stream>>>(binBase, ebuf, hp, dinv, b1, h1p);
    k_agg2    <<<NBKT, 256, 0, stream>>>(binBase, ebuf, h1p, dinv, W2, b2, out);
}

// Round 7
// 510.551 us; speedup vs baseline: 3.2845x; 3.2845x over previous
//
#include <hip/hip_runtime.h>

#define NN 200000
#define NE 6400000
#define FIN 256
#define HID 16
#define NC 40
#define NBKT 782        // ceil(NN/256) dst-buckets of 256 nodes
#define NCHUNK 2048     // microchunks
#define EPC 3125        // edges per microchunk: 2048*3125 = 6.4M exact
#define CPT 8           // chunks per thread in btotal/cscan (2048/256)
#define STAGE_CAP 9472  // bucket stage capacity (mean 8192, ~14 sigma)

// ---- 1. per-microchunk coarse histogram over 782 dst-buckets (LDS atomics only) ----
__global__ __launch_bounds__(256) void k_chist(const int* __restrict__ dst,
                                               int* __restrict__ hist_g) {
    __shared__ int sh[NBKT];
    int c = blockIdx.x;
    for (int j = threadIdx.x; j < NBKT; j += 256) sh[j] = 0;
    __syncthreads();
    int beg = c * EPC;
    for (int e = beg + threadIdx.x; e < beg + EPC; e += 256)
        atomicAdd(&sh[dst[e] >> 8], 1);
    __syncthreads();
    for (int j = threadIdx.x; j < NBKT; j += 256)
        hist_g[c * NBKT + j] = sh[j];
}

// ---- 2. bucket totals: block per bucket, tree reduce over 2048 chunks ----
__global__ __launch_bounds__(256) void k_btotal(const int* __restrict__ hist_g,
                                                int* __restrict__ totals) {
    __shared__ int sm[256];
    int b = blockIdx.x, t = threadIdx.x;
    int s = 0;
#pragma unroll
    for (int j = 0; j < CPT; ++j)
        s += hist_g[(t * CPT + j) * NBKT + b];
    sm[t] = s;
    __syncthreads();
    for (int off = 128; off > 0; off >>= 1) {
        if (t < off) sm[t] += sm[t + off];
        __syncthreads();
    }
    if (t == 0) totals[b] = sm[0];
}

// ---- 3. exclusive scan of 782 totals -> binBase ----
__global__ __launch_bounds__(1024) void k_bscan(const int* __restrict__ totals,
                                                int* __restrict__ binBase) {
    __shared__ int sm[1024];
    int t = threadIdx.x;
    int v = (t < NBKT) ? totals[t] : 0;
    sm[t] = v;
    __syncthreads();
    for (int off = 1; off < 1024; off <<= 1) {
        int x = (t >= off) ? sm[t - off] : 0;
        __syncthreads();
        sm[t] += x;
        __syncthreads();
    }
    if (t < NBKT) binBase[t] = sm[t] - v;
    if (t == 0) binBase[NBKT] = NE;
}

// ---- 4. per-bucket scan over 2048 microchunks, in place: hist -> cursor bases ----
__global__ __launch_bounds__(256) void k_cscan(int* __restrict__ hist_g,
                                               const int* __restrict__ binBase) {
    __shared__ int sm[256];
    int b = blockIdx.x, t = threadIdx.x;
    int loc[CPT];
    int s = 0;
#pragma unroll
    for (int j = 0; j < CPT; ++j) {
        loc[j] = hist_g[(t * CPT + j) * NBKT + b];
        s += loc[j];
    }
    sm[t] = s;
    __syncthreads();
    for (int off = 1; off < 256; off <<= 1) {
        int x = (t >= off) ? sm[t - off] : 0;
        __syncthreads();
        sm[t] += x;
        __syncthreads();
    }
    int base = binBase[b] + sm[t] - s;
#pragma unroll
    for (int j = 0; j < CPT; ++j) {
        hist_g[(t * CPT + j) * NBKT + b] = base;
        base += loc[j];
    }
}

// ---- 5. coarse scatter with LDS-local counting sort + coalesced write-out.
// One block per 3125-edge chunk: count -> scan -> rank into sorted LDS stage ->
// linear write-out (bucket via binary search; wave stores hit ~16 lines, not 64).
__global__ __launch_bounds__(256) void k_cscatter(const int* __restrict__ src,
                                                  const int* __restrict__ dst,
                                                  const float* __restrict__ w,
                                                  const int* __restrict__ coff,
                                                  int2* __restrict__ ebuf) {
    __shared__ int2 srec[EPC];      // 25000 B sorted stage
    __shared__ int sbase[NBKT];     // counts -> local exclusive base
    __shared__ int scur[NBKT];      // rank cursors
    __shared__ int sgb[NBKT];       // global base - local base
    __shared__ int sm[256];
    int c = blockIdx.x, t = threadIdx.x;
    for (int j = t; j < NBKT; j += 256) sbase[j] = 0;
    __syncthreads();
    int beg = c * EPC;
    // pass 1: count
    for (int e = beg + t; e < beg + EPC; e += 256)
        atomicAdd(&sbase[dst[e] >> 8], 1);
    __syncthreads();
    // scan 782 counts: 4 slots per thread + block Hillis-Steele
    int l[4];
    int s = 0;
#pragma unroll
    for (int q = 0; q < 4; ++q) {
        int j = t * 4 + q;
        l[q] = (j < NBKT) ? sbase[j] : 0;
        s += l[q];
    }
    sm[t] = s;
    __syncthreads();
    for (int off = 1; off < 256; off <<= 1) {
        int x = (t >= off) ? sm[t - off] : 0;
        __syncthreads();
        sm[t] += x;
        __syncthreads();
    }
    int base = sm[t] - s;   // exclusive prefix for this thread's 4 slots
#pragma unroll
    for (int q = 0; q < 4; ++q) {
        int j = t * 4 + q;
        if (j < NBKT) {
            sbase[j] = base;
            scur[j]  = base;
            sgb[j]   = coff[c * NBKT + j] - base;
        }
        base += l[q];
    }
    __syncthreads();
    // pass 2: rank & scatter into sorted LDS (record = {src | dl<<18, w})
    for (int e = beg + t; e < beg + EPC; e += 256) {
        int d = dst[e];
        int k = atomicAdd(&scur[d >> 8], 1);
        srec[k] = make_int2(src[e] | ((d & 255) << 18), __float_as_int(w[e]));
    }
    __syncthreads();
    // pass 3: linear write-out; bucket(k) = rightmost b with sbase[b] <= k
    for (int k = t; k < EPC; k += 256) {
        int lo = 0, hi = NBKT;
        while (hi - lo > 1) {
            int mid = (lo + hi) >> 1;
            if (sbase[mid] <= k) lo = mid; else hi = mid;
        }
        ebuf[sgb[lo] + k] = srec[k];
    }
}

// ---- 6. per-bucket: fine counts + weighted degree (LDS) -> dinv, row_start ----
__global__ __launch_bounds__(256) void k_bucket(const int* __restrict__ binBase,
                                                const int2* __restrict__ ebuf,
                                                float* __restrict__ dinv,
                                                int* __restrict__ row_start) {
    __shared__ int scnt[256];
    __shared__ float sdeg[256];
    __shared__ int ssc[256];
    int b = blockIdx.x, t = threadIdx.x;
    scnt[t] = 0;
    sdeg[t] = 1.0f;  // self-loop weight
    __syncthreads();
    int beg = binBase[b], end = binBase[b + 1];
    for (int e = beg + t; e < end; e += 256) {
        int2 r = ebuf[e];
        int dl = (r.x >> 18) & 255;
        atomicAdd(&scnt[dl], 1);
        atomicAdd(&sdeg[dl], __int_as_float(r.y));
    }
    __syncthreads();
    int node = b * 256 + t;
    if (node < NN) dinv[node] = rsqrtf(sdeg[t]);  // deg >= 1 always
    int v = scnt[t];
    ssc[t] = v;
    __syncthreads();
    for (int off = 1; off < 256; off <<= 1) {
        int x = (t >= off) ? ssc[t - off] : 0;
        __syncthreads();
        ssc[t] += x;
        __syncthreads();
    }
    if (node < NN) row_start[node] = beg + ssc[t] - v;
    if (b == NBKT - 1 && t == 0) row_start[NN] = NE;
}

// ---- 7. per-bucket node-sort, in place, fully coalesced write-back ----
__global__ __launch_bounds__(256) void k_bscatter(const int* __restrict__ binBase,
                                                  const int* __restrict__ row_start,
                                                  int2* __restrict__ ebuf) {
    __shared__ int2 srec[STAGE_CAP];   // sorted stage (75776 B)
    __shared__ int scur[256];
    int b = blockIdx.x, t = threadIdx.x;
    int beg = binBase[b], end = binBase[b + 1];
    int cnt = end - beg;
    int node = b * 256 + t;
    scur[t] = (node < NN) ? (row_start[node] - beg) : 0;
    __syncthreads();
    for (int j = t; j < cnt; j += 256) {
        int2 r = ebuf[beg + j];
        int dl = (r.x >> 18) & 255;
        int k = atomicAdd(&scur[dl], 1);
        srec[k] = r;
    }
    __syncthreads();
    for (int j = t; j < cnt; j += 256)
        ebuf[beg + j] = srec[j];
}

// ---- 8. h' = dinv[row] * (x @ W1) ----
__global__ __launch_bounds__(256) void k_gemm1(const float* __restrict__ x,
                                               const float* __restrict__ W1,
                                               const float* __restrict__ dinv,
                                               float* __restrict__ hp) {
    int row = blockIdx.x * 256 + threadIdx.x;
    if (row >= NN) return;
    float acc[HID];
#pragma unroll
    for (int f = 0; f < HID; ++f) acc[f] = 0.0f;
    const float4* x4 = reinterpret_cast<const float4*>(x + (size_t)row * FIN);
    for (int kk = 0; kk < FIN / 4; ++kk) {
        float4 xv = x4[kk];
#pragma unroll
        for (int j = 0; j < 4; ++j) {
            float xs = (j == 0) ? xv.x : (j == 1) ? xv.y : (j == 2) ? xv.z : xv.w;
            int k = kk * 4 + j;
#pragma unroll
            for (int f = 0; f < HID; ++f)
                acc[f] = fmaf(xs, W1[k * HID + f], acc[f]);
        }
    }
    float di = dinv[row];
    float4* out4 = reinterpret_cast<float4*>(hp + (size_t)row * HID);
#pragma unroll
    for (int q = 0; q < HID / 4; ++q)
        out4[q] = make_float4(acc[q*4]*di, acc[q*4+1]*di, acc[q*4+2]*di, acc[q*4+3]*di);
}

// ---- 9. gather layer 1: h1' = dinv * relu( dinv*(sum_e w*h'[src] + h'[i]) + b1 ) ----
__global__ __launch_bounds__(256) void k_gather1(const int* __restrict__ row_start,
                                                 const int2* __restrict__ edges,
                                                 const float* __restrict__ hp,
                                                 const float* __restrict__ dinv,
                                                 const float* __restrict__ b1,
                                                 float* __restrict__ h1p) {
    int t = blockIdx.x * 256 + threadIdx.x;   // grid exact: 4*NN threads
    int i = t >> 2;
    int sub = t & 3;
    int beg = row_start[i];
    int end = row_start[i + 1];
    float4 a0 = make_float4(0.f,0.f,0.f,0.f), a1 = a0, a2 = a0, a3 = a0;
    if (sub == 0) {  // self-loop seed: h'[i] (weight 1 in folded form)
        const float4* hv = reinterpret_cast<const float4*>(hp + (size_t)i * HID);
        a0 = hv[0]; a1 = hv[1]; a2 = hv[2]; a3 = hv[3];
    }
    int p = beg + sub;
    for (; p + 4 < end; p += 8) {  // 2 edges per iter: both rows in flight
        int2 ea = edges[p];
        int2 eb = edges[p + 4];
        float na = __int_as_float(ea.y);
        float nb = __int_as_float(eb.y);
        const float4* ha = reinterpret_cast<const float4*>(hp + (size_t)(ea.x & 0x3FFFF) * HID);
        const float4* hb = reinterpret_cast<const float4*>(hp + (size_t)(eb.x & 0x3FFFF) * HID);
        float4 u0 = ha[0], u1 = ha[1], u2 = ha[2], u3 = ha[3];
        float4 v0 = hb[0], v1 = hb[1], v2 = hb[2], v3 = hb[3];
        a0.x = fmaf(u0.x, na, a0.x); a0.y = fmaf(u0.y, na, a0.y);
        a0.z = fmaf(u0.z, na, a0.z); a0.w = fmaf(u0.w, na, a0.w);
        a1.x = fmaf(u1.x, na, a1.x); a1.y = fmaf(u1.y, na, a1.y);
        a1.z = fmaf(u1.z, na, a1.z); a1.w = fmaf(u1.w, na, a1.w);
        a2.x = fmaf(u2.x, na, a2.x); a2.y = fmaf(u2.y, na, a2.y);
        a2.z = fmaf(u2.z, na, a2.z); a2.w = fmaf(u2.w, na, a2.w);
        a3.x = fmaf(u3.x, na, a3.x); a3.y = fmaf(u3.y, na, a3.y);
        a3.z = fmaf(u3.z, na, a3.z); a3.w = fmaf(u3.w, na, a3.w);
        a0.x = fmaf(v0.x, nb, a0.x); a0.y = fmaf(v0.y, nb, a0.y);
        a0.z = fmaf(v0.z, nb, a0.z); a0.w = fmaf(v0.w, nb, a0.w);
        a1.x = fmaf(v1.x, nb, a1.x); a1.y = fmaf(v1.y, nb, a1.y);
        a1.z = fmaf(v1.z, nb, a1.z); a1.w = fmaf(v1.w, nb, a1.w);
        a2.x = fmaf(v2.x, nb, a2.x); a2.y = fmaf(v2.y, nb, a2.y);
        a2.z = fmaf(v2.z, nb, a2.z); a2.w = fmaf(v2.w, nb, a2.w);
        a3.x = fmaf(v3.x, nb, a3.x); a3.y = fmaf(v3.y, nb, a3.y);
        a3.z = fmaf(v3.z, nb, a3.z); a3.w = fmaf(v3.w, nb, a3.w);
    }
    if (p < end) {
        int2 ev = edges[p];
        float nv = __int_as_float(ev.y);
        const float4* hv = reinterpret_cast<const float4*>(hp + (size_t)(ev.x & 0x3FFFF) * HID);
        float4 u0 = hv[0], u1 = hv[1], u2 = hv[2], u3 = hv[3];
        a0.x = fmaf(u0.x, nv, a0.x); a0.y = fmaf(u0.y, nv, a0.y);
        a0.z = fmaf(u0.z, nv, a0.z); a0.w = fmaf(u0.w, nv, a0.w);
        a1.x = fmaf(u1.x, nv, a1.x); a1.y = fmaf(u1.y, nv, a1.y);
        a1.z = fmaf(u1.z, nv, a1.z); a1.w = fmaf(u1.w, nv, a1.w);
        a2.x = fmaf(u2.x, nv, a2.x); a2.y = fmaf(u2.y, nv, a2.y);
        a2.z = fmaf(u2.z, nv, a2.z); a2.w = fmaf(u2.w, nv, a2.w);
        a3.x = fmaf(u3.x, nv, a3.x); a3.y = fmaf(u3.y, nv, a3.y);
        a3.z = fmaf(u3.z, nv, a3.z); a3.w = fmaf(u3.w, nv, a3.w);
    }
#pragma unroll
    for (int m = 1; m <= 2; m <<= 1) {
        a0.x += __shfl_xor(a0.x, m); a0.y += __shfl_xor(a0.y, m);
        a0.z += __shfl_xor(a0.z, m); a0.w += __shfl_xor(a0.w, m);
        a1.x += __shfl_xor(a1.x, m); a1.y += __shfl_xor(a1.y, m);
        a1.z += __shfl_xor(a1.z, m); a1.w += __shfl_xor(a1.w, m);
        a2.x += __shfl_xor(a2.x, m); a2.y += __shfl_xor(a2.y, m);
        a2.z += __shfl_xor(a2.z, m); a2.w += __shfl_xor(a2.w, m);
        a3.x += __shfl_xor(a3.x, m); a3.y += __shfl_xor(a3.y, m);
        a3.z += __shfl_xor(a3.z, m); a3.w += __shfl_xor(a3.w, m);
    }
    float4 q = (sub == 0) ? a0 : (sub == 1) ? a1 : (sub == 2) ? a2 : a3;
    float di = dinv[i];
    float4 bb = reinterpret_cast<const float4*>(b1)[sub];
    q.x = di * fmaxf(fmaf(di, q.x, bb.x), 0.f);
    q.y = di * fmaxf(fmaf(di, q.y, bb.y), 0.f);
    q.z = di * fmaxf(fmaf(di, q.z, bb.z), 0.f);
    q.w = di * fmaxf(fmaf(di, q.w, bb.w), 0.f);
    reinterpret_cast<float4*>(h1p + (size_t)i * HID)[sub] = q;
}

// ---- 10. gather layer 2 fused with GEMM2: out = (dinv*(sum + h1'[i])) @ W2 + b2 ----
__global__ __launch_bounds__(256) void k_gather2(const int* __restrict__ row_start,
                                                 const int2* __restrict__ edges,
                                                 const float* __restrict__ h1p,
                                                 const float* __restrict__ dinv,
                                                 const float* __restrict__ W2,
                                                 const float* __restrict__ b2,
                                                 float* __restrict__ out) {
    __shared__ float sW2[HID * NC];
    __shared__ float sb2[NC];
    {
        int tt = threadIdx.x;
        for (int j = tt; j < HID * NC; j += 256) sW2[j] = W2[j];
        if (tt < NC) sb2[tt] = b2[tt];
    }
    __syncthreads();
    int t = blockIdx.x * 256 + threadIdx.x;
    int i = t >> 2;
    int sub = t & 3;
    int beg = row_start[i];
    int end = row_start[i + 1];
    float4 a0 = make_float4(0.f,0.f,0.f,0.f), a1 = a0, a2 = a0, a3 = a0;
    if (sub == 0) {
        const float4* hv = reinterpret_cast<const float4*>(h1p + (size_t)i * HID);
        a0 = hv[0]; a1 = hv[1]; a2 = hv[2]; a3 = hv[3];
    }
    int p = beg + sub;
    for (; p + 4 < end; p += 8) {
        int2 ea = edges[p];
        int2 eb = edges[p + 4];
        float na = __int_as_float(ea.y);
        float nb = __int_as_float(eb.y);
        const float4* ha = reinterpret_cast<const float4*>(h1p + (size_t)(ea.x & 0x3FFFF) * HID);
        const float4* hb = reinterpret_cast<const float4*>(h1p + (size_t)(eb.x & 0x3FFFF) * HID);
        float4 u0 = ha[0], u1 = ha[1], u2 = ha[2], u3 = ha[3];
        float4 v0 = hb[0], v1 = hb[1], v2 = hb[2], v3 = hb[3];
        a0.x = fmaf(u0.x, na, a0.x); a0.y = fmaf(u0.y, na, a0.y);
        a0.z = fmaf(u0.z, na, a0.z); a0.w = fmaf(u0.w, na, a0.w);
        a1.x = fmaf(u1.x, na, a1.x); a1.y = fmaf(u1.y, na, a1.y);
        a1.z = fmaf(u1.z, na, a1.z); a1.w = fmaf(u1.w, na, a1.w);
        a2.x = fmaf(u2.x, na, a2.x); a2.y = fmaf(u2.y, na, a2.y);
        a2.z = fmaf(u2.z, na, a2.z); a2.w = fmaf(u2.w, na, a2.w);
        a3.x = fmaf(u3.x, na, a3.x); a3.y = fmaf(u3.y, na, a3.y);
        a3.z = fmaf(u3.z, na, a3.z); a3.w = fmaf(u3.w, na, a3.w);
        a0.x = fmaf(v0.x, nb, a0.x); a0.y = fmaf(v0.y, nb, a0.y);
        a0.z = fmaf(v0.z, nb, a0.z); a0.w = fmaf(v0.w, nb, a0.w);
        a1.x = fmaf(v1.x, nb, a1.x); a1.y = fmaf(v1.y, nb, a1.y);
        a1.z = fmaf(v1.z, nb, a1.z); a1.w = fmaf(v1.w, nb, a1.w);
        a2.x = fmaf(v2.x, nb, a2.x); a2.y = fmaf(v2.y, nb, a2.y);
        a2.z = fmaf(v2.z, nb, a2.z); a2.w = fmaf(v2.w, nb, a2.w);
        a3.x = fmaf(v3.x, nb, a3.x); a3.y = fmaf(v3.y, nb, a3.y);
        a3.z = fmaf(v3.z, nb, a3.z); a3.w = fmaf(v3.w, nb, a3.w);
    }
    if (p < end) {
        int2 ev = edges[p];
        float nv = __int_as_float(ev.y);
        const float4* hv = reinterpret_cast<const float4*>(h1p + (size_t)(ev.x & 0x3FFFF) * HID);
        float4 u0 = hv[0], u1 = hv[1], u2 = hv[2], u3 = hv[3];
        a0.x = fmaf(u0.x, nv, a0.x); a0.y = fmaf(u0.y, nv, a0.y);
        a0.z = fmaf(u0.z, nv, a0.z); a0.w = fmaf(u0.w, nv, a0.w);
        a1.x = fmaf(u1.x, nv, a1.x); a1.y = fmaf(u1.y, nv, a1.y);
        a1.z = fmaf(u1.z, nv, a1.z); a1.w = fmaf(u1.w, nv, a1.w);
        a2.x = fmaf(u2.x, nv, a2.x); a2.y = fmaf(u2.y, nv, a2.y);
        a2.z = fmaf(u2.z, nv, a2.z); a2.w = fmaf(u2.w, nv, a2.w);
        a3.x = fmaf(u3.x, nv, a3.x); a3.y = fmaf(u3.y, nv, a3.y);
        a3.z = fmaf(u3.z, nv, a3.z); a3.w = fmaf(u3.w, nv, a3.w);
    }
#pragma unroll
    for (int m = 1; m <= 2; m <<= 1) {
        a0.x += __shfl_xor(a0.x, m); a0.y += __shfl_xor(a0.y, m);
        a0.z += __shfl_xor(a0.z, m); a0.w += __shfl_xor(a0.w, m);
        a1.x += __shfl_xor(a1.x, m); a1.y += __shfl_xor(a1.y, m);
        a1.z += __shfl_xor(a1.z, m); a1.w += __shfl_xor(a1.w, m);
        a2.x += __shfl_xor(a2.x, m); a2.y += __shfl_xor(a2.y, m);
        a2.z += __shfl_xor(a2.z, m); a2.w += __shfl_xor(a2.w, m);
        a3.x += __shfl_xor(a3.x, m); a3.y += __shfl_xor(a3.y, m);
        a3.z += __shfl_xor(a3.z, m); a3.w += __shfl_xor(a3.w, m);
    }
    float di = dinv[i];
    float av[HID] = { a0.x, a0.y, a0.z, a0.w, a1.x, a1.y, a1.z, a1.w,
                      a2.x, a2.y, a2.z, a2.w, a3.x, a3.y, a3.z, a3.w };
#pragma unroll
    for (int k = 0; k < HID; ++k) av[k] *= di;
    float* op = out + (size_t)i * NC + sub * 10;
#pragma unroll
    for (int c = 0; c < 10; ++c) {
        int col = sub * 10 + c;
        float s = sb2[col];
#pragma unroll
        for (int k = 0; k < HID; ++k)
            s = fmaf(av[k], sW2[k * NC + col], s);
        op[c] = s;
    }
}

// ---- launch ----
extern "C" void kernel_launch(void* const* d_in, const int* in_sizes, int n_in,
                              void* d_out, int out_size, void* d_ws, size_t ws_size,
                              hipStream_t stream) {
    const float* x  = (const float*)d_in[0];
    const int*   ei = (const int*)d_in[1];
    const float* w  = (const float*)d_in[2];
    const float* W1 = (const float*)d_in[3];
    const float* b1 = (const float*)d_in[4];
    const float* b2 = (const float*)d_in[6];
    const float* W2 = (const float*)d_in[5];
    float* out = (float*)d_out;

    const int* src = ei;
    const int* dst = ei + NE;

    // workspace layout (4B words), ~78.4 MB.
    // hist_g (2048*782 = 1,601,536 words) ALIASED into hp region
    // (hist_g dead after k_cscatter; hp first written by k_gemm1, later).
    char* wsb = (char*)d_ws;
    float* dinv      = (float*)(wsb);                      // 200064
    int*   row_start = (int*)  (wsb + 200064LL * 4);       // 200064 (NN+1 used)
    int*   totals    = (int*)  (wsb + 400128LL * 4);       // 1024
    int*   binBase   = (int*)  (wsb + 401152LL * 4);       // 1024 (NBKT+1 used)
    int2*  ebuf      = (int2*) (wsb + 402176LL * 4);       // NE int2 = 12.8M words
    float* hp        = (float*)(wsb + 13202176LL * 4);     // NN*HID (3.2M words)
    int*   hist_g    = (int*)  (wsb + 13202176LL * 4);     // aliases hp
    float* h1p       = (float*)(wsb + 16402176LL * 4);     // NN*HID

    const int BN = (NN + 255) / 256;   // 782
    const int BG = (4 * NN) / 256;     // 3125 exact

    k_chist   <<<NCHUNK, 256, 0, stream>>>(dst, hist_g);
    k_btotal  <<<NBKT, 256, 0, stream>>>(hist_g, totals);
    k_bscan   <<<1, 1024, 0, stream>>>(totals, binBase);
    k_cscan   <<<NBKT, 256, 0, stream>>>(hist_g, binBase);
    k_cscatter<<<NCHUNK, 256, 0, stream>>>(src, dst, w, hist_g, ebuf);
    k_bucket  <<<NBKT, 256, 0, stream>>>(binBase, ebuf, dinv, row_start);
    k_bscatter<<<NBKT, 256, 0, stream>>>(binBase, row_start, ebuf);
    k_gemm1   <<<BN, 256, 0, stream>>>(x, W1, dinv, hp);
    k_gather1 <<<BG, 256, 0, stream>>>(row_start, ebuf, hp, dinv, b1, h1p);
    k_gather2 <<<BG, 256, 0, stream>>>(row_start, ebuf, h1p, dinv, W2, b2, out);
}